// Round 17
// baseline (1098.324 us; speedup 1.0000x reference)
//
#include <hip/hip_runtime.h>

// GCN autoencoder: recon = (Z @ Z^T).  Front (K1-K4) = EXACT R13, ~58us.
// R17: zzt restructure from R16's PMC row (VGPR=172 -> 8 waves/CU;
// VALUBusy 43.5%; WRITE 3.9 TB/s; FETCH ~0; conflicts minor). Diagnosis:
// compute(~45us) and store-drain(~58us) phases serialize at 2 blocks/CU.
// Fix: (a) j-half split - compute+store 32-reg acc per half, store burst
// split and overlapped with next half's compute; (b) __launch_bounds__(256,4)
// forces VGPR<=128 -> 16 waves/CU -> 2x outstanding stores.

constexpr int N_   = 10000;
constexpr int E_   = 320000;
constexpr int F_   = 512;
constexpr int H1_  = 32;
constexpr int H2_  = 16;
constexpr int CAP_ = 96;   // ELL row capacity; P[Poisson(32) > 96] ~ 3e-20

typedef float f32x4 __attribute__((ext_vector_type(4)));

// ---------------- K1: h = X @ W1 (4 cols/thread), side blocks zero cursor --
constexpr int GEMM_THREADS = N_ * (H1_ / 4);            // 80000
constexpr int GEMM_BLOCKS  = (GEMM_THREADS + 255) / 256; // 313
constexpr int ZERO_BLOCKS  = (N_ + 255) / 256;           // 40

__global__ __launch_bounds__(256) void gemm_xw1_zero(const float* __restrict__ x,
                                                     const float* __restrict__ W1,
                                                     float* __restrict__ h,
                                                     int* __restrict__ cursor) {
    if (blockIdx.x >= GEMM_BLOCKS) {
        int i = (blockIdx.x - GEMM_BLOCKS) * 256 + threadIdx.x;
        if (i < N_) cursor[i] = 0;
        return;
    }
    int tid = blockIdx.x * blockDim.x + threadIdx.x;
    if (tid >= GEMM_THREADS) return;
    int r  = tid >> 3;              // /8
    int cq = (tid & 7) * 4;         // column quad 0,4,...,28
    const float4* xr = reinterpret_cast<const float4*>(x + (size_t)r * F_);
    float4 acc = make_float4(0.f, 0.f, 0.f, 0.f);
#pragma unroll 4
    for (int k4 = 0; k4 < F_ / 4; ++k4) {
        float4 xv = xr[k4];
        int k = k4 * 4;
        float4 w0 = *reinterpret_cast<const float4*>(W1 + (k + 0) * H1_ + cq);
        float4 w1 = *reinterpret_cast<const float4*>(W1 + (k + 1) * H1_ + cq);
        float4 w2 = *reinterpret_cast<const float4*>(W1 + (k + 2) * H1_ + cq);
        float4 w3 = *reinterpret_cast<const float4*>(W1 + (k + 3) * H1_ + cq);
        acc.x = fmaf(xv.x, w0.x, acc.x); acc.y = fmaf(xv.x, w0.y, acc.y);
        acc.z = fmaf(xv.x, w0.z, acc.z); acc.w = fmaf(xv.x, w0.w, acc.w);
        acc.x = fmaf(xv.y, w1.x, acc.x); acc.y = fmaf(xv.y, w1.y, acc.y);
        acc.z = fmaf(xv.y, w1.z, acc.z); acc.w = fmaf(xv.y, w1.w, acc.w);
        acc.x = fmaf(xv.z, w2.x, acc.x); acc.y = fmaf(xv.z, w2.y, acc.y);
        acc.z = fmaf(xv.z, w2.z, acc.z); acc.w = fmaf(xv.z, w2.w, acc.w);
        acc.x = fmaf(xv.w, w3.x, acc.x); acc.y = fmaf(xv.w, w3.y, acc.y);
        acc.z = fmaf(xv.w, w3.z, acc.z); acc.w = fmaf(xv.w, w3.w, acc.w);
    }
    *reinterpret_cast<float4*>(h + (size_t)r * H1_ + cq) = acc;
}

// ---------------- K2: scatter edges into ELL rows ----------------
__global__ __launch_bounds__(256) void scatter_ell(const int* __restrict__ erow,
                                                   const int* __restrict__ ecol,
                                                   const float* __restrict__ ew,
                                                   int* __restrict__ cursor,
                                                   int* __restrict__ cole,
                                                   float* __restrict__ we) {
    int e = blockIdx.x * blockDim.x + threadIdx.x;
    if (e >= E_) return;
    int r = erow[e];
    int p = atomicAdd(&cursor[r], 1);
    if (p < CAP_) {                       // overflow-impossible guard
        size_t idx = (size_t)r * CAP_ + p;
        cole[idx] = ecol[e];
        we[idx]   = ew[e];
    }
}

// ---------------- K3: h2 = relu(A @ h) @ W2  (8 rows / block) --------------
__global__ __launch_bounds__(256) void spmm1_mlp(const float* __restrict__ h,
                                                 const int* __restrict__ cursor,
                                                 const int* __restrict__ cole,
                                                 const float* __restrict__ we,
                                                 const float* __restrict__ W2,
                                                 float* __restrict__ h2) {
    __shared__ float sh1[8][H1_ + 1];
    __shared__ float sW2[H1_ * H2_];
    const int t = threadIdx.x;
    sW2[t]       = W2[t];
    sW2[t + 256] = W2[t + 256];

    const int rl = t >> 5;           // 0..7
    const int f  = t & (H1_ - 1);
    const int r  = blockIdx.x * 8 + rl;
    float acc = 0.f;
    if (r < N_) {
        const int deg = cursor[r];
        const int*   cp = cole + (size_t)r * CAP_;   // 384B-aligned
        const float* wp = we   + (size_t)r * CAP_;
        int p = 0;
        for (; p + 8 <= deg; p += 8) {
            int4   c0 = *reinterpret_cast<const int4*>(cp + p);
            int4   c1 = *reinterpret_cast<const int4*>(cp + p + 4);
            float4 w0 = *reinterpret_cast<const float4*>(wp + p);
            float4 w1 = *reinterpret_cast<const float4*>(wp + p + 4);
            float g0 = h[(size_t)c0.x * H1_ + f];
            float g1 = h[(size_t)c0.y * H1_ + f];
            float g2 = h[(size_t)c0.z * H1_ + f];
            float g3 = h[(size_t)c0.w * H1_ + f];
            float g4 = h[(size_t)c1.x * H1_ + f];
            float g5 = h[(size_t)c1.y * H1_ + f];
            float g6 = h[(size_t)c1.z * H1_ + f];
            float g7 = h[(size_t)c1.w * H1_ + f];
            acc = fmaf(w0.x, g0, acc);
            acc = fmaf(w0.y, g1, acc);
            acc = fmaf(w0.z, g2, acc);
            acc = fmaf(w0.w, g3, acc);
            acc = fmaf(w1.x, g4, acc);
            acc = fmaf(w1.y, g5, acc);
            acc = fmaf(w1.z, g6, acc);
            acc = fmaf(w1.w, g7, acc);
        }
        for (; p < deg; ++p)
            acc = fmaf(wp[p], h[(size_t)cp[p] * H1_ + f], acc);
    }
    sh1[rl][f] = fmaxf(acc, 0.f);     // relu fused here
    __syncthreads();

    if (t < 128) {
        const int r2l = t >> 4;       // 0..7
        const int c   = t & (H2_ - 1);
        const int r2  = blockIdx.x * 8 + r2l;
        if (r2 < N_) {
            float a = 0.f;
#pragma unroll
            for (int k = 0; k < H1_; ++k)
                a = fmaf(sh1[r2l][k], sW2[k * H2_ + c], a);
            h2[(size_t)r2 * H2_ + c] = a;
        }
    }
}

// ---------------- K4: z = A @ h2  (16 rows / block) ----------------
__global__ __launch_bounds__(256) void spmm2(const float* __restrict__ h2,
                                             const int* __restrict__ cursor,
                                             const int* __restrict__ cole,
                                             const float* __restrict__ we,
                                             float* __restrict__ z) {
    const int t = threadIdx.x;
    const int rl = t >> 4;            // 0..15
    const int f  = t & (H2_ - 1);
    const int r  = blockIdx.x * 16 + rl;
    if (r >= N_) return;
    const int deg = cursor[r];
    const int*   cp = cole + (size_t)r * CAP_;
    const float* wp = we   + (size_t)r * CAP_;
    float acc = 0.f;
    int p = 0;
    for (; p + 8 <= deg; p += 8) {
        int4   c0 = *reinterpret_cast<const int4*>(cp + p);
        int4   c1 = *reinterpret_cast<const int4*>(cp + p + 4);
        float4 w0 = *reinterpret_cast<const float4*>(wp + p);
        float4 w1 = *reinterpret_cast<const float4*>(wp + p + 4);
        float g0 = h2[(size_t)c0.x * H2_ + f];
        float g1 = h2[(size_t)c0.y * H2_ + f];
        float g2 = h2[(size_t)c0.z * H2_ + f];
        float g3 = h2[(size_t)c0.w * H2_ + f];
        float g4 = h2[(size_t)c1.x * H2_ + f];
        float g5 = h2[(size_t)c1.y * H2_ + f];
        float g6 = h2[(size_t)c1.z * H2_ + f];
        float g7 = h2[(size_t)c1.w * H2_ + f];
        acc = fmaf(w0.x, g0, acc);
        acc = fmaf(w0.y, g1, acc);
        acc = fmaf(w0.z, g2, acc);
        acc = fmaf(w0.w, g3, acc);
        acc = fmaf(w1.x, g4, acc);
        acc = fmaf(w1.y, g5, acc);
        acc = fmaf(w1.z, g6, acc);
        acc = fmaf(w1.w, g7, acc);
    }
    for (; p < deg; ++p)
        acc = fmaf(wp[p], h2[(size_t)cp[p] * H2_ + f], acc);
    z[(size_t)r * H2_ + f] = acc;
}

// ---------------- K5: out = z @ z^T  (64x256, j-half split, <=128 VGPR) ----
constexpr int BI = 64;
constexpr int BJ = 256;

__global__ __launch_bounds__(256, 4) void zzt(const float* __restrict__ z,
                                              float* __restrict__ out) {
    __shared__ float zi[H2_][BI + 4];    // 16 x 68
    __shared__ float zj[H2_][BJ + 8];    // 16 x 264
    const int t  = threadIdx.x;
    const int ib = blockIdx.y * BI;
    const int jb = blockIdx.x * BJ;

    // stage zi: 64 rows x 16k. thread -> (row = t>>2, kq = (t&3)*4)
    {
        int row = t >> 2;
        int kq  = (t & 3) * 4;
        int gr  = ib + row;
        float4 v = (gr < N_)
            ? *reinterpret_cast<const float4*>(z + (size_t)gr * H2_ + kq)
            : make_float4(0.f, 0.f, 0.f, 0.f);
        zi[kq + 0][row] = v.x;
        zi[kq + 1][row] = v.y;
        zi[kq + 2][row] = v.z;
        zi[kq + 3][row] = v.w;
    }
    // stage zj: 256 rows x 16k, 4 iterations
#pragma unroll
    for (int it = 0; it < 4; ++it) {
        int idx = it * 256 + t;
        int row = idx >> 2;
        int kq  = (idx & 3) * 4;
        int gr  = jb + row;
        float4 v = (gr < N_)
            ? *reinterpret_cast<const float4*>(z + (size_t)gr * H2_ + kq)
            : make_float4(0.f, 0.f, 0.f, 0.f);
        zj[kq + 0][row] = v.x;
        zj[kq + 1][row] = v.y;
        zj[kq + 2][row] = v.z;
        zj[kq + 3][row] = v.w;
    }
    __syncthreads();

    const int tj = t & 31;          // 32 j-lanes
    const int i0 = (t >> 5) * 8;    // 8 i-groups of 8 rows

#pragma unroll 1                    // keep halves SEQUENTIAL: 32 live acc regs
    for (int jh = 0; jh < 2; ++jh) {
        const int jbase = jh * 128;
        float4 acc[8] = {};

#pragma unroll
        for (int k = 0; k < H2_; ++k) {
            float4 b  = *reinterpret_cast<const float4*>(&zj[k][jbase + tj * 4]);
            float4 a0 = *reinterpret_cast<const float4*>(&zi[k][i0]);      // bcast
            float4 a1 = *reinterpret_cast<const float4*>(&zi[k][i0 + 4]);  // bcast
#pragma unroll
            for (int ii = 0; ii < 8; ++ii) {
                float av = (ii == 0) ? a0.x : (ii == 1) ? a0.y
                         : (ii == 2) ? a0.z : (ii == 3) ? a0.w
                         : (ii == 4) ? a1.x : (ii == 5) ? a1.y
                         : (ii == 6) ? a1.z : a1.w;
                acc[ii].x = fmaf(av, b.x, acc[ii].x);
                acc[ii].y = fmaf(av, b.y, acc[ii].y);
                acc[ii].z = fmaf(av, b.z, acc[ii].z);
                acc[ii].w = fmaf(av, b.w, acc[ii].w);
            }
        }

        const int j0 = jb + jbase + tj * 4;
#pragma unroll
        for (int ii = 0; ii < 8; ++ii) {
            int gi = ib + i0 + ii;
            if (gi >= N_) break;
            float* orow = out + (size_t)gi * N_;
            if (j0 + 3 < N_) {
                f32x4 v = {acc[ii].x, acc[ii].y, acc[ii].z, acc[ii].w};
                __builtin_nontemporal_store(v, reinterpret_cast<f32x4*>(orow + j0));
            } else {
                float a[4] = {acc[ii].x, acc[ii].y, acc[ii].z, acc[ii].w};
                for (int jj = 0; jj < 4; ++jj)
                    if (j0 + jj < N_) orow[j0 + jj] = a[jj];
            }
        }
    }
}

extern "C" void kernel_launch(void* const* d_in, const int* in_sizes, int n_in,
                              void* d_out, int out_size, void* d_ws, size_t ws_size,
                              hipStream_t stream) {
    const float* x    = (const float*)d_in[0];
    const float* ew   = (const float*)d_in[1];
    const float* W1   = (const float*)d_in[2];
    const float* W2   = (const float*)d_in[3];
    const int*   erow = (const int*)d_in[4];
    const int*   ecol = (const int*)d_in[5];
    float* out = (float*)d_out;

    // workspace layout (4B elements) — same as R13
    float* h      = (float*)d_ws;              // N*H1
    float* h2     = h  + (size_t)N_ * H1_;     // N*H2
    float* z      = h2 + (size_t)N_ * H2_;     // N*H2
    float* we     = z  + (size_t)N_ * H2_;     // N*CAP
    int*   cole   = (int*)(we + (size_t)N_ * CAP_);   // N*CAP
    int*   cursor = cole + (size_t)N_ * CAP_;  // N

    gemm_xw1_zero<<<GEMM_BLOCKS + ZERO_BLOCKS, 256, 0, stream>>>(x, W1, h, cursor);
    scatter_ell<<<(E_ + 255) / 256, 256, 0, stream>>>(erow, ecol, ew, cursor, cole, we);
    spmm1_mlp<<<(N_ + 7) / 8, 256, 0, stream>>>(h, cursor, cole, we, W2, h2);
    spmm2<<<(N_ + 15) / 16, 256, 0, stream>>>(h2, cursor, cole, we, z);

    dim3 grid((N_ + BJ - 1) / BJ, (N_ + BI - 1) / BI);   // 40 x 157
    zzt<<<grid, 256, 0, stream>>>(z, out);
}

// Round 18
// 205.677 us; speedup vs baseline: 5.3400x; 5.3400x over previous
//
#include <hip/hip_runtime.h>

// GCN autoencoder: recon = (Z @ Z^T).  Front (K1-K4) = EXACT R13 (~58us).
// R18: undo R17's launch_bounds disaster (VGPR forced 64 -> 1.7GB scratch
// spill traffic, 1098us). Back to R13 (194us) with ONE isolated change:
// zzt stores PLAIN instead of nontemporal. nt was never solo-tested (came
// in with the 64x256 tile in R10). Theory: plain write-allocate stores
// complete into L2 (full 64B lines, no RMW - R16 FETCH~0 proves coverage),
// L2 absorbs bursts while VALU proceeds; nt forces synchronous HBM-pace
// drain. If >200us, nt was helping -> revert next round.

constexpr int N_   = 10000;
constexpr int E_   = 320000;
constexpr int F_   = 512;
constexpr int H1_  = 32;
constexpr int H2_  = 16;
constexpr int CAP_ = 96;   // ELL row capacity; P[Poisson(32) > 96] ~ 3e-20

// ---------------- K1: h = X @ W1 (4 cols/thread), side blocks zero cursor --
constexpr int GEMM_THREADS = N_ * (H1_ / 4);            // 80000
constexpr int GEMM_BLOCKS  = (GEMM_THREADS + 255) / 256; // 313
constexpr int ZERO_BLOCKS  = (N_ + 255) / 256;           // 40

__global__ __launch_bounds__(256) void gemm_xw1_zero(const float* __restrict__ x,
                                                     const float* __restrict__ W1,
                                                     float* __restrict__ h,
                                                     int* __restrict__ cursor) {
    if (blockIdx.x >= GEMM_BLOCKS) {
        int i = (blockIdx.x - GEMM_BLOCKS) * 256 + threadIdx.x;
        if (i < N_) cursor[i] = 0;
        return;
    }
    int tid = blockIdx.x * blockDim.x + threadIdx.x;
    if (tid >= GEMM_THREADS) return;
    int r  = tid >> 3;              // /8
    int cq = (tid & 7) * 4;         // column quad 0,4,...,28
    const float4* xr = reinterpret_cast<const float4*>(x + (size_t)r * F_);
    float4 acc = make_float4(0.f, 0.f, 0.f, 0.f);
#pragma unroll 4
    for (int k4 = 0; k4 < F_ / 4; ++k4) {
        float4 xv = xr[k4];
        int k = k4 * 4;
        float4 w0 = *reinterpret_cast<const float4*>(W1 + (k + 0) * H1_ + cq);
        float4 w1 = *reinterpret_cast<const float4*>(W1 + (k + 1) * H1_ + cq);
        float4 w2 = *reinterpret_cast<const float4*>(W1 + (k + 2) * H1_ + cq);
        float4 w3 = *reinterpret_cast<const float4*>(W1 + (k + 3) * H1_ + cq);
        acc.x = fmaf(xv.x, w0.x, acc.x); acc.y = fmaf(xv.x, w0.y, acc.y);
        acc.z = fmaf(xv.x, w0.z, acc.z); acc.w = fmaf(xv.x, w0.w, acc.w);
        acc.x = fmaf(xv.y, w1.x, acc.x); acc.y = fmaf(xv.y, w1.y, acc.y);
        acc.z = fmaf(xv.y, w1.z, acc.z); acc.w = fmaf(xv.y, w1.w, acc.w);
        acc.x = fmaf(xv.z, w2.x, acc.x); acc.y = fmaf(xv.z, w2.y, acc.y);
        acc.z = fmaf(xv.z, w2.z, acc.z); acc.w = fmaf(xv.z, w2.w, acc.w);
        acc.x = fmaf(xv.w, w3.x, acc.x); acc.y = fmaf(xv.w, w3.y, acc.y);
        acc.z = fmaf(xv.w, w3.z, acc.z); acc.w = fmaf(xv.w, w3.w, acc.w);
    }
    *reinterpret_cast<float4*>(h + (size_t)r * H1_ + cq) = acc;
}

// ---------------- K2: scatter edges into ELL rows ----------------
__global__ __launch_bounds__(256) void scatter_ell(const int* __restrict__ erow,
                                                   const int* __restrict__ ecol,
                                                   const float* __restrict__ ew,
                                                   int* __restrict__ cursor,
                                                   int* __restrict__ cole,
                                                   float* __restrict__ we) {
    int e = blockIdx.x * blockDim.x + threadIdx.x;
    if (e >= E_) return;
    int r = erow[e];
    int p = atomicAdd(&cursor[r], 1);
    if (p < CAP_) {                       // overflow-impossible guard
        size_t idx = (size_t)r * CAP_ + p;
        cole[idx] = ecol[e];
        we[idx]   = ew[e];
    }
}

// ---------------- K3: h2 = relu(A @ h) @ W2  (8 rows / block) --------------
__global__ __launch_bounds__(256) void spmm1_mlp(const float* __restrict__ h,
                                                 const int* __restrict__ cursor,
                                                 const int* __restrict__ cole,
                                                 const float* __restrict__ we,
                                                 const float* __restrict__ W2,
                                                 float* __restrict__ h2) {
    __shared__ float sh1[8][H1_ + 1];
    __shared__ float sW2[H1_ * H2_];
    const int t = threadIdx.x;
    sW2[t]       = W2[t];
    sW2[t + 256] = W2[t + 256];

    const int rl = t >> 5;           // 0..7
    const int f  = t & (H1_ - 1);
    const int r  = blockIdx.x * 8 + rl;
    float acc = 0.f;
    if (r < N_) {
        const int deg = cursor[r];
        const int*   cp = cole + (size_t)r * CAP_;   // 384B-aligned
        const float* wp = we   + (size_t)r * CAP_;
        int p = 0;
        for (; p + 8 <= deg; p += 8) {
            int4   c0 = *reinterpret_cast<const int4*>(cp + p);
            int4   c1 = *reinterpret_cast<const int4*>(cp + p + 4);
            float4 w0 = *reinterpret_cast<const float4*>(wp + p);
            float4 w1 = *reinterpret_cast<const float4*>(wp + p + 4);
            float g0 = h[(size_t)c0.x * H1_ + f];
            float g1 = h[(size_t)c0.y * H1_ + f];
            float g2 = h[(size_t)c0.z * H1_ + f];
            float g3 = h[(size_t)c0.w * H1_ + f];
            float g4 = h[(size_t)c1.x * H1_ + f];
            float g5 = h[(size_t)c1.y * H1_ + f];
            float g6 = h[(size_t)c1.z * H1_ + f];
            float g7 = h[(size_t)c1.w * H1_ + f];
            acc = fmaf(w0.x, g0, acc);
            acc = fmaf(w0.y, g1, acc);
            acc = fmaf(w0.z, g2, acc);
            acc = fmaf(w0.w, g3, acc);
            acc = fmaf(w1.x, g4, acc);
            acc = fmaf(w1.y, g5, acc);
            acc = fmaf(w1.z, g6, acc);
            acc = fmaf(w1.w, g7, acc);
        }
        for (; p < deg; ++p)
            acc = fmaf(wp[p], h[(size_t)cp[p] * H1_ + f], acc);
    }
    sh1[rl][f] = fmaxf(acc, 0.f);     // relu fused here
    __syncthreads();

    if (t < 128) {
        const int r2l = t >> 4;       // 0..7
        const int c   = t & (H2_ - 1);
        const int r2  = blockIdx.x * 8 + r2l;
        if (r2 < N_) {
            float a = 0.f;
#pragma unroll
            for (int k = 0; k < H1_; ++k)
                a = fmaf(sh1[r2l][k], sW2[k * H2_ + c], a);
            h2[(size_t)r2 * H2_ + c] = a;
        }
    }
}

// ---------------- K4: z = A @ h2  (16 rows / block) ----------------
__global__ __launch_bounds__(256) void spmm2(const float* __restrict__ h2,
                                             const int* __restrict__ cursor,
                                             const int* __restrict__ cole,
                                             const float* __restrict__ we,
                                             float* __restrict__ z) {
    const int t = threadIdx.x;
    const int rl = t >> 4;            // 0..15
    const int f  = t & (H2_ - 1);
    const int r  = blockIdx.x * 16 + rl;
    if (r >= N_) return;
    const int deg = cursor[r];
    const int*   cp = cole + (size_t)r * CAP_;
    const float* wp = we   + (size_t)r * CAP_;
    float acc = 0.f;
    int p = 0;
    for (; p + 8 <= deg; p += 8) {
        int4   c0 = *reinterpret_cast<const int4*>(cp + p);
        int4   c1 = *reinterpret_cast<const int4*>(cp + p + 4);
        float4 w0 = *reinterpret_cast<const float4*>(wp + p);
        float4 w1 = *reinterpret_cast<const float4*>(wp + p + 4);
        float g0 = h2[(size_t)c0.x * H2_ + f];
        float g1 = h2[(size_t)c0.y * H2_ + f];
        float g2 = h2[(size_t)c0.z * H2_ + f];
        float g3 = h2[(size_t)c0.w * H2_ + f];
        float g4 = h2[(size_t)c1.x * H2_ + f];
        float g5 = h2[(size_t)c1.y * H2_ + f];
        float g6 = h2[(size_t)c1.z * H2_ + f];
        float g7 = h2[(size_t)c1.w * H2_ + f];
        acc = fmaf(w0.x, g0, acc);
        acc = fmaf(w0.y, g1, acc);
        acc = fmaf(w0.z, g2, acc);
        acc = fmaf(w0.w, g3, acc);
        acc = fmaf(w1.x, g4, acc);
        acc = fmaf(w1.y, g5, acc);
        acc = fmaf(w1.z, g6, acc);
        acc = fmaf(w1.w, g7, acc);
    }
    for (; p < deg; ++p)
        acc = fmaf(wp[p], h2[(size_t)cp[p] * H2_ + f], acc);
    z[(size_t)r * H2_ + f] = acc;
}

// ---------------- K5: out = z @ z^T  (64x256, 8x8/thread, PLAIN stores) ----
constexpr int BI = 64;
constexpr int BJ = 256;

__global__ __launch_bounds__(256) void zzt(const float* __restrict__ z,
                                           float* __restrict__ out) {
    __shared__ float zi[H2_][BI + 4];    // 16 x 68
    __shared__ float zj[H2_][BJ + 8];    // 16 x 264
    const int t  = threadIdx.x;
    const int ib = blockIdx.y * BI;
    const int jb = blockIdx.x * BJ;

    // stage zi: 64 rows x 16k. thread -> (row = t>>2, kq = (t&3)*4)
    {
        int row = t >> 2;
        int kq  = (t & 3) * 4;
        int gr  = ib + row;
        float4 v = (gr < N_)
            ? *reinterpret_cast<const float4*>(z + (size_t)gr * H2_ + kq)
            : make_float4(0.f, 0.f, 0.f, 0.f);
        zi[kq + 0][row] = v.x;
        zi[kq + 1][row] = v.y;
        zi[kq + 2][row] = v.z;
        zi[kq + 3][row] = v.w;
    }
    // stage zj: 256 rows x 16k, 4 iterations
#pragma unroll
    for (int it = 0; it < 4; ++it) {
        int idx = it * 256 + t;
        int row = idx >> 2;
        int kq  = (idx & 3) * 4;
        int gr  = jb + row;
        float4 v = (gr < N_)
            ? *reinterpret_cast<const float4*>(z + (size_t)gr * H2_ + kq)
            : make_float4(0.f, 0.f, 0.f, 0.f);
        zj[kq + 0][row] = v.x;
        zj[kq + 1][row] = v.y;
        zj[kq + 2][row] = v.z;
        zj[kq + 3][row] = v.w;
    }
    __syncthreads();

    const int tj = t & 31;          // 32 j-lanes
    const int i0 = (t >> 5) * 8;    // 8 i-groups of 8 rows

    float4 accA[8] = {};            // j = jb + tj*4 .. +3
    float4 accB[8] = {};            // j = jb + 128 + tj*4 .. +3

#pragma unroll
    for (int k = 0; k < H2_; ++k) {
        float4 b0 = *reinterpret_cast<const float4*>(&zj[k][tj * 4]);
        float4 b1 = *reinterpret_cast<const float4*>(&zj[k][128 + tj * 4]);
        float4 a0 = *reinterpret_cast<const float4*>(&zi[k][i0]);      // bcast
        float4 a1 = *reinterpret_cast<const float4*>(&zi[k][i0 + 4]);  // bcast
        float av[8] = {a0.x, a0.y, a0.z, a0.w, a1.x, a1.y, a1.z, a1.w};
#pragma unroll
        for (int ii = 0; ii < 8; ++ii) {
            accA[ii].x = fmaf(av[ii], b0.x, accA[ii].x);
            accA[ii].y = fmaf(av[ii], b0.y, accA[ii].y);
            accA[ii].z = fmaf(av[ii], b0.z, accA[ii].z);
            accA[ii].w = fmaf(av[ii], b0.w, accA[ii].w);
            accB[ii].x = fmaf(av[ii], b1.x, accB[ii].x);
            accB[ii].y = fmaf(av[ii], b1.y, accB[ii].y);
            accB[ii].z = fmaf(av[ii], b1.z, accB[ii].z);
            accB[ii].w = fmaf(av[ii], b1.w, accB[ii].w);
        }
    }

    const int j0 = jb + tj * 4;
    const int j1 = jb + 128 + tj * 4;
#pragma unroll
    for (int ii = 0; ii < 8; ++ii) {
        int gi = ib + i0 + ii;
        if (gi >= N_) break;
        float* orow = out + (size_t)gi * N_;
        if (j0 + 3 < N_) {
            *reinterpret_cast<float4*>(orow + j0) =
                make_float4(accA[ii].x, accA[ii].y, accA[ii].z, accA[ii].w);
        } else {
            float a[4] = {accA[ii].x, accA[ii].y, accA[ii].z, accA[ii].w};
            for (int jj = 0; jj < 4; ++jj)
                if (j0 + jj < N_) orow[j0 + jj] = a[jj];
        }
        if (j1 + 3 < N_) {
            *reinterpret_cast<float4*>(orow + j1) =
                make_float4(accB[ii].x, accB[ii].y, accB[ii].z, accB[ii].w);
        } else {
            float b[4] = {accB[ii].x, accB[ii].y, accB[ii].z, accB[ii].w};
            for (int jj = 0; jj < 4; ++jj)
                if (j1 + jj < N_) orow[j1 + jj] = b[jj];
        }
    }
}

extern "C" void kernel_launch(void* const* d_in, const int* in_sizes, int n_in,
                              void* d_out, int out_size, void* d_ws, size_t ws_size,
                              hipStream_t stream) {
    const float* x    = (const float*)d_in[0];
    const float* ew   = (const float*)d_in[1];
    const float* W1   = (const float*)d_in[2];
    const float* W2   = (const float*)d_in[3];
    const int*   erow = (const int*)d_in[4];
    const int*   ecol = (const int*)d_in[5];
    float* out = (float*)d_out;

    // workspace layout (4B elements) — same as R13
    float* h      = (float*)d_ws;              // N*H1
    float* h2     = h  + (size_t)N_ * H1_;     // N*H2
    float* z      = h2 + (size_t)N_ * H2_;     // N*H2
    float* we     = z  + (size_t)N_ * H2_;     // N*CAP
    int*   cole   = (int*)(we + (size_t)N_ * CAP_);   // N*CAP
    int*   cursor = cole + (size_t)N_ * CAP_;  // N

    gemm_xw1_zero<<<GEMM_BLOCKS + ZERO_BLOCKS, 256, 0, stream>>>(x, W1, h, cursor);
    scatter_ell<<<(E_ + 255) / 256, 256, 0, stream>>>(erow, ecol, ew, cursor, cole, we);
    spmm1_mlp<<<(N_ + 7) / 8, 256, 0, stream>>>(h, cursor, cole, we, W2, h2);
    spmm2<<<(N_ + 15) / 16, 256, 0, stream>>>(h2, cursor, cole, we, z);

    dim3 grid((N_ + BJ - 1) / BJ, (N_ + BI - 1) / BI);   // 40 x 157
    zzt<<<grid, 256, 0, stream>>>(z, out);
}

// Round 19
// 198.418 us; speedup vs baseline: 5.5354x; 1.0366x over previous
//
#include <hip/hip_runtime.h>

// GCN autoencoder: recon = (Z @ Z^T).  Front (K1-K4) = EXACT R13 (~58us).
// R19: zzt = R13's 64x256 tile + nt stores (A/B-proven best, R18: plain
// stores +12us) with the j-half split from R17 but NO launch_bounds
// pressure (R17's forced 64 VGPR -> 1.7GB scratch spills, 1098us).
// Sequential halves: 32 live acc regs instead of 64 -> natural VGPR
// ~110-130, crossing the <=128 occupancy step -> 16 waves/CU (was 8 at
// VGPR=172). 2x outstanding stores + half-1 compute overlaps half-0
// store drain. R16 PMC basis: VALU ~45us, stores ~58us, serialization
// at 2 blocks/CU was the gap.

constexpr int N_   = 10000;
constexpr int E_   = 320000;
constexpr int F_   = 512;
constexpr int H1_  = 32;
constexpr int H2_  = 16;
constexpr int CAP_ = 96;   // ELL row capacity; P[Poisson(32) > 96] ~ 3e-20

typedef float f32x4 __attribute__((ext_vector_type(4)));

// ---------------- K1: h = X @ W1 (4 cols/thread), side blocks zero cursor --
constexpr int GEMM_THREADS = N_ * (H1_ / 4);            // 80000
constexpr int GEMM_BLOCKS  = (GEMM_THREADS + 255) / 256; // 313
constexpr int ZERO_BLOCKS  = (N_ + 255) / 256;           // 40

__global__ __launch_bounds__(256) void gemm_xw1_zero(const float* __restrict__ x,
                                                     const float* __restrict__ W1,
                                                     float* __restrict__ h,
                                                     int* __restrict__ cursor) {
    if (blockIdx.x >= GEMM_BLOCKS) {
        int i = (blockIdx.x - GEMM_BLOCKS) * 256 + threadIdx.x;
        if (i < N_) cursor[i] = 0;
        return;
    }
    int tid = blockIdx.x * blockDim.x + threadIdx.x;
    if (tid >= GEMM_THREADS) return;
    int r  = tid >> 3;              // /8
    int cq = (tid & 7) * 4;         // column quad 0,4,...,28
    const float4* xr = reinterpret_cast<const float4*>(x + (size_t)r * F_);
    float4 acc = make_float4(0.f, 0.f, 0.f, 0.f);
#pragma unroll 4
    for (int k4 = 0; k4 < F_ / 4; ++k4) {
        float4 xv = xr[k4];
        int k = k4 * 4;
        float4 w0 = *reinterpret_cast<const float4*>(W1 + (k + 0) * H1_ + cq);
        float4 w1 = *reinterpret_cast<const float4*>(W1 + (k + 1) * H1_ + cq);
        float4 w2 = *reinterpret_cast<const float4*>(W1 + (k + 2) * H1_ + cq);
        float4 w3 = *reinterpret_cast<const float4*>(W1 + (k + 3) * H1_ + cq);
        acc.x = fmaf(xv.x, w0.x, acc.x); acc.y = fmaf(xv.x, w0.y, acc.y);
        acc.z = fmaf(xv.x, w0.z, acc.z); acc.w = fmaf(xv.x, w0.w, acc.w);
        acc.x = fmaf(xv.y, w1.x, acc.x); acc.y = fmaf(xv.y, w1.y, acc.y);
        acc.z = fmaf(xv.y, w1.z, acc.z); acc.w = fmaf(xv.y, w1.w, acc.w);
        acc.x = fmaf(xv.z, w2.x, acc.x); acc.y = fmaf(xv.z, w2.y, acc.y);
        acc.z = fmaf(xv.z, w2.z, acc.z); acc.w = fmaf(xv.z, w2.w, acc.w);
        acc.x = fmaf(xv.w, w3.x, acc.x); acc.y = fmaf(xv.w, w3.y, acc.y);
        acc.z = fmaf(xv.w, w3.z, acc.z); acc.w = fmaf(xv.w, w3.w, acc.w);
    }
    *reinterpret_cast<float4*>(h + (size_t)r * H1_ + cq) = acc;
}

// ---------------- K2: scatter edges into ELL rows ----------------
__global__ __launch_bounds__(256) void scatter_ell(const int* __restrict__ erow,
                                                   const int* __restrict__ ecol,
                                                   const float* __restrict__ ew,
                                                   int* __restrict__ cursor,
                                                   int* __restrict__ cole,
                                                   float* __restrict__ we) {
    int e = blockIdx.x * blockDim.x + threadIdx.x;
    if (e >= E_) return;
    int r = erow[e];
    int p = atomicAdd(&cursor[r], 1);
    if (p < CAP_) {                       // overflow-impossible guard
        size_t idx = (size_t)r * CAP_ + p;
        cole[idx] = ecol[e];
        we[idx]   = ew[e];
    }
}

// ---------------- K3: h2 = relu(A @ h) @ W2  (8 rows / block) --------------
__global__ __launch_bounds__(256) void spmm1_mlp(const float* __restrict__ h,
                                                 const int* __restrict__ cursor,
                                                 const int* __restrict__ cole,
                                                 const float* __restrict__ we,
                                                 const float* __restrict__ W2,
                                                 float* __restrict__ h2) {
    __shared__ float sh1[8][H1_ + 1];
    __shared__ float sW2[H1_ * H2_];
    const int t = threadIdx.x;
    sW2[t]       = W2[t];
    sW2[t + 256] = W2[t + 256];

    const int rl = t >> 5;           // 0..7
    const int f  = t & (H1_ - 1);
    const int r  = blockIdx.x * 8 + rl;
    float acc = 0.f;
    if (r < N_) {
        const int deg = cursor[r];
        const int*   cp = cole + (size_t)r * CAP_;   // 384B-aligned
        const float* wp = we   + (size_t)r * CAP_;
        int p = 0;
        for (; p + 8 <= deg; p += 8) {
            int4   c0 = *reinterpret_cast<const int4*>(cp + p);
            int4   c1 = *reinterpret_cast<const int4*>(cp + p + 4);
            float4 w0 = *reinterpret_cast<const float4*>(wp + p);
            float4 w1 = *reinterpret_cast<const float4*>(wp + p + 4);
            float g0 = h[(size_t)c0.x * H1_ + f];
            float g1 = h[(size_t)c0.y * H1_ + f];
            float g2 = h[(size_t)c0.z * H1_ + f];
            float g3 = h[(size_t)c0.w * H1_ + f];
            float g4 = h[(size_t)c1.x * H1_ + f];
            float g5 = h[(size_t)c1.y * H1_ + f];
            float g6 = h[(size_t)c1.z * H1_ + f];
            float g7 = h[(size_t)c1.w * H1_ + f];
            acc = fmaf(w0.x, g0, acc);
            acc = fmaf(w0.y, g1, acc);
            acc = fmaf(w0.z, g2, acc);
            acc = fmaf(w0.w, g3, acc);
            acc = fmaf(w1.x, g4, acc);
            acc = fmaf(w1.y, g5, acc);
            acc = fmaf(w1.z, g6, acc);
            acc = fmaf(w1.w, g7, acc);
        }
        for (; p < deg; ++p)
            acc = fmaf(wp[p], h[(size_t)cp[p] * H1_ + f], acc);
    }
    sh1[rl][f] = fmaxf(acc, 0.f);     // relu fused here
    __syncthreads();

    if (t < 128) {
        const int r2l = t >> 4;       // 0..7
        const int c   = t & (H2_ - 1);
        const int r2  = blockIdx.x * 8 + r2l;
        if (r2 < N_) {
            float a = 0.f;
#pragma unroll
            for (int k = 0; k < H1_; ++k)
                a = fmaf(sh1[r2l][k], sW2[k * H2_ + c], a);
            h2[(size_t)r2 * H2_ + c] = a;
        }
    }
}

// ---------------- K4: z = A @ h2  (16 rows / block) ----------------
__global__ __launch_bounds__(256) void spmm2(const float* __restrict__ h2,
                                             const int* __restrict__ cursor,
                                             const int* __restrict__ cole,
                                             const float* __restrict__ we,
                                             float* __restrict__ z) {
    const int t = threadIdx.x;
    const int rl = t >> 4;            // 0..15
    const int f  = t & (H2_ - 1);
    const int r  = blockIdx.x * 16 + rl;
    if (r >= N_) return;
    const int deg = cursor[r];
    const int*   cp = cole + (size_t)r * CAP_;
    const float* wp = we   + (size_t)r * CAP_;
    float acc = 0.f;
    int p = 0;
    for (; p + 8 <= deg; p += 8) {
        int4   c0 = *reinterpret_cast<const int4*>(cp + p);
        int4   c1 = *reinterpret_cast<const int4*>(cp + p + 4);
        float4 w0 = *reinterpret_cast<const float4*>(wp + p);
        float4 w1 = *reinterpret_cast<const float4*>(wp + p + 4);
        float g0 = h2[(size_t)c0.x * H2_ + f];
        float g1 = h2[(size_t)c0.y * H2_ + f];
        float g2 = h2[(size_t)c0.z * H2_ + f];
        float g3 = h2[(size_t)c0.w * H2_ + f];
        float g4 = h2[(size_t)c1.x * H2_ + f];
        float g5 = h2[(size_t)c1.y * H2_ + f];
        float g6 = h2[(size_t)c1.z * H2_ + f];
        float g7 = h2[(size_t)c1.w * H2_ + f];
        acc = fmaf(w0.x, g0, acc);
        acc = fmaf(w0.y, g1, acc);
        acc = fmaf(w0.z, g2, acc);
        acc = fmaf(w0.w, g3, acc);
        acc = fmaf(w1.x, g4, acc);
        acc = fmaf(w1.y, g5, acc);
        acc = fmaf(w1.z, g6, acc);
        acc = fmaf(w1.w, g7, acc);
    }
    for (; p < deg; ++p)
        acc = fmaf(wp[p], h2[(size_t)cp[p] * H2_ + f], acc);
    z[(size_t)r * H2_ + f] = acc;
}

// ---------------- K5: out = z @ z^T  (64x256, j-half split, nt stores) -----
constexpr int BI = 64;
constexpr int BJ = 256;

__global__ __launch_bounds__(256) void zzt(const float* __restrict__ z,
                                           float* __restrict__ out) {
    __shared__ float zi[H2_][BI + 4];    // 16 x 68
    __shared__ float zj[H2_][BJ + 8];    // 16 x 264
    const int t  = threadIdx.x;
    const int ib = blockIdx.y * BI;
    const int jb = blockIdx.x * BJ;

    // stage zi: 64 rows x 16k. thread -> (row = t>>2, kq = (t&3)*4)
    {
        int row = t >> 2;
        int kq  = (t & 3) * 4;
        int gr  = ib + row;
        float4 v = (gr < N_)
            ? *reinterpret_cast<const float4*>(z + (size_t)gr * H2_ + kq)
            : make_float4(0.f, 0.f, 0.f, 0.f);
        zi[kq + 0][row] = v.x;
        zi[kq + 1][row] = v.y;
        zi[kq + 2][row] = v.z;
        zi[kq + 3][row] = v.w;
    }
    // stage zj: 256 rows x 16k, 4 iterations
#pragma unroll
    for (int it = 0; it < 4; ++it) {
        int idx = it * 256 + t;
        int row = idx >> 2;
        int kq  = (idx & 3) * 4;
        int gr  = jb + row;
        float4 v = (gr < N_)
            ? *reinterpret_cast<const float4*>(z + (size_t)gr * H2_ + kq)
            : make_float4(0.f, 0.f, 0.f, 0.f);
        zj[kq + 0][row] = v.x;
        zj[kq + 1][row] = v.y;
        zj[kq + 2][row] = v.z;
        zj[kq + 3][row] = v.w;
    }
    __syncthreads();

    const int tj = t & 31;          // 32 j-lanes
    const int i0 = (t >> 5) * 8;    // 8 i-groups of 8 rows

#pragma unroll 1                    // halves SEQUENTIAL: 32 live acc regs
    for (int jh = 0; jh < 2; ++jh) {
        const int jbase = jh * 128;
        float4 acc[8] = {};

#pragma unroll
        for (int k = 0; k < H2_; ++k) {
            float4 b  = *reinterpret_cast<const float4*>(&zj[k][jbase + tj * 4]);
            float4 a0 = *reinterpret_cast<const float4*>(&zi[k][i0]);      // bcast
            float4 a1 = *reinterpret_cast<const float4*>(&zi[k][i0 + 4]);  // bcast
            float av[8] = {a0.x, a0.y, a0.z, a0.w, a1.x, a1.y, a1.z, a1.w};
#pragma unroll
            for (int ii = 0; ii < 8; ++ii) {
                acc[ii].x = fmaf(av[ii], b.x, acc[ii].x);
                acc[ii].y = fmaf(av[ii], b.y, acc[ii].y);
                acc[ii].z = fmaf(av[ii], b.z, acc[ii].z);
                acc[ii].w = fmaf(av[ii], b.w, acc[ii].w);
            }
        }

        const int j0 = jb + jbase + tj * 4;
#pragma unroll
        for (int ii = 0; ii < 8; ++ii) {
            int gi = ib + i0 + ii;
            if (gi >= N_) break;
            float* orow = out + (size_t)gi * N_;
            if (j0 + 3 < N_) {
                f32x4 v = {acc[ii].x, acc[ii].y, acc[ii].z, acc[ii].w};
                __builtin_nontemporal_store(v, reinterpret_cast<f32x4*>(orow + j0));
            } else {
                float a[4] = {acc[ii].x, acc[ii].y, acc[ii].z, acc[ii].w};
                for (int jj = 0; jj < 4; ++jj)
                    if (j0 + jj < N_) orow[j0 + jj] = a[jj];
            }
        }
    }
}

extern "C" void kernel_launch(void* const* d_in, const int* in_sizes, int n_in,
                              void* d_out, int out_size, void* d_ws, size_t ws_size,
                              hipStream_t stream) {
    const float* x    = (const float*)d_in[0];
    const float* ew   = (const float*)d_in[1];
    const float* W1   = (const float*)d_in[2];
    const float* W2   = (const float*)d_in[3];
    const int*   erow = (const int*)d_in[4];
    const int*   ecol = (const int*)d_in[5];
    float* out = (float*)d_out;

    // workspace layout (4B elements) — same as R13
    float* h      = (float*)d_ws;              // N*H1
    float* h2     = h  + (size_t)N_ * H1_;     // N*H2
    float* z      = h2 + (size_t)N_ * H2_;     // N*H2
    float* we     = z  + (size_t)N_ * H2_;     // N*CAP
    int*   cole   = (int*)(we + (size_t)N_ * CAP_);   // N*CAP
    int*   cursor = cole + (size_t)N_ * CAP_;  // N

    gemm_xw1_zero<<<GEMM_BLOCKS + ZERO_BLOCKS, 256, 0, stream>>>(x, W1, h, cursor);
    scatter_ell<<<(E_ + 255) / 256, 256, 0, stream>>>(erow, ecol, ew, cursor, cole, we);
    spmm1_mlp<<<(N_ + 7) / 8, 256, 0, stream>>>(h, cursor, cole, we, W2, h2);
    spmm2<<<(N_ + 15) / 16, 256, 0, stream>>>(h2, cursor, cole, we, z);

    dim3 grid((N_ + BJ - 1) / BJ, (N_ + BI - 1) / BI);   // 40 x 157
    zzt<<<grid, 256, 0, stream>>>(z, out);
}

// Round 20
// 189.067 us; speedup vs baseline: 5.8092x; 1.0495x over previous
//
#include <hip/hip_runtime.h>

// GCN autoencoder: recon = (Z @ Z^T).  Front (K1-K4) = EXACT R13 (~58us).
// R20 = R13 (best, 194us) + ONE change: XCD-chunked block swizzle in zzt.
// Default dispatch round-robins consecutive blocks over 8 XCDs -> adjacent
// 1KB column-strips of the same out-rows are written from different XCDs
// (interleaved write streams per HBM channel). Swizzle hw_id ->
// (hw_id%8)*785 + hw_id/8 (6280%8==0, bijective) gives each XCD a
// contiguous ~50MB horizontal band -> sequential per-XCD writeback.
// zzt ledger: nt stores +12 (keep), 64x256 tile +22 (keep); strip/reg-zi/
// launch-bounds/j-split all neutral or worse. Warm zzt 90 vs 58 floor.

constexpr int N_   = 10000;
constexpr int E_   = 320000;
constexpr int F_   = 512;
constexpr int H1_  = 32;
constexpr int H2_  = 16;
constexpr int CAP_ = 96;   // ELL row capacity; P[Poisson(32) > 96] ~ 3e-20

typedef float f32x4 __attribute__((ext_vector_type(4)));

// ---------------- K1: h = X @ W1 (4 cols/thread), side blocks zero cursor --
constexpr int GEMM_THREADS = N_ * (H1_ / 4);            // 80000
constexpr int GEMM_BLOCKS  = (GEMM_THREADS + 255) / 256; // 313
constexpr int ZERO_BLOCKS  = (N_ + 255) / 256;           // 40

__global__ __launch_bounds__(256) void gemm_xw1_zero(const float* __restrict__ x,
                                                     const float* __restrict__ W1,
                                                     float* __restrict__ h,
                                                     int* __restrict__ cursor) {
    if (blockIdx.x >= GEMM_BLOCKS) {
        int i = (blockIdx.x - GEMM_BLOCKS) * 256 + threadIdx.x;
        if (i < N_) cursor[i] = 0;
        return;
    }
    int tid = blockIdx.x * blockDim.x + threadIdx.x;
    if (tid >= GEMM_THREADS) return;
    int r  = tid >> 3;              // /8
    int cq = (tid & 7) * 4;         // column quad 0,4,...,28
    const float4* xr = reinterpret_cast<const float4*>(x + (size_t)r * F_);
    float4 acc = make_float4(0.f, 0.f, 0.f, 0.f);
#pragma unroll 4
    for (int k4 = 0; k4 < F_ / 4; ++k4) {
        float4 xv = xr[k4];
        int k = k4 * 4;
        float4 w0 = *reinterpret_cast<const float4*>(W1 + (k + 0) * H1_ + cq);
        float4 w1 = *reinterpret_cast<const float4*>(W1 + (k + 1) * H1_ + cq);
        float4 w2 = *reinterpret_cast<const float4*>(W1 + (k + 2) * H1_ + cq);
        float4 w3 = *reinterpret_cast<const float4*>(W1 + (k + 3) * H1_ + cq);
        acc.x = fmaf(xv.x, w0.x, acc.x); acc.y = fmaf(xv.x, w0.y, acc.y);
        acc.z = fmaf(xv.x, w0.z, acc.z); acc.w = fmaf(xv.x, w0.w, acc.w);
        acc.x = fmaf(xv.y, w1.x, acc.x); acc.y = fmaf(xv.y, w1.y, acc.y);
        acc.z = fmaf(xv.y, w1.z, acc.z); acc.w = fmaf(xv.y, w1.w, acc.w);
        acc.x = fmaf(xv.z, w2.x, acc.x); acc.y = fmaf(xv.z, w2.y, acc.y);
        acc.z = fmaf(xv.z, w2.z, acc.z); acc.w = fmaf(xv.z, w2.w, acc.w);
        acc.x = fmaf(xv.w, w3.x, acc.x); acc.y = fmaf(xv.w, w3.y, acc.y);
        acc.z = fmaf(xv.w, w3.z, acc.z); acc.w = fmaf(xv.w, w3.w, acc.w);
    }
    *reinterpret_cast<float4*>(h + (size_t)r * H1_ + cq) = acc;
}

// ---------------- K2: scatter edges into ELL rows ----------------
__global__ __launch_bounds__(256) void scatter_ell(const int* __restrict__ erow,
                                                   const int* __restrict__ ecol,
                                                   const float* __restrict__ ew,
                                                   int* __restrict__ cursor,
                                                   int* __restrict__ cole,
                                                   float* __restrict__ we) {
    int e = blockIdx.x * blockDim.x + threadIdx.x;
    if (e >= E_) return;
    int r = erow[e];
    int p = atomicAdd(&cursor[r], 1);
    if (p < CAP_) {                       // overflow-impossible guard
        size_t idx = (size_t)r * CAP_ + p;
        cole[idx] = ecol[e];
        we[idx]   = ew[e];
    }
}

// ---------------- K3: h2 = relu(A @ h) @ W2  (8 rows / block) --------------
__global__ __launch_bounds__(256) void spmm1_mlp(const float* __restrict__ h,
                                                 const int* __restrict__ cursor,
                                                 const int* __restrict__ cole,
                                                 const float* __restrict__ we,
                                                 const float* __restrict__ W2,
                                                 float* __restrict__ h2) {
    __shared__ float sh1[8][H1_ + 1];
    __shared__ float sW2[H1_ * H2_];
    const int t = threadIdx.x;
    sW2[t]       = W2[t];
    sW2[t + 256] = W2[t + 256];

    const int rl = t >> 5;           // 0..7
    const int f  = t & (H1_ - 1);
    const int r  = blockIdx.x * 8 + rl;
    float acc = 0.f;
    if (r < N_) {
        const int deg = cursor[r];
        const int*   cp = cole + (size_t)r * CAP_;   // 384B-aligned
        const float* wp = we   + (size_t)r * CAP_;
        int p = 0;
        for (; p + 8 <= deg; p += 8) {
            int4   c0 = *reinterpret_cast<const int4*>(cp + p);
            int4   c1 = *reinterpret_cast<const int4*>(cp + p + 4);
            float4 w0 = *reinterpret_cast<const float4*>(wp + p);
            float4 w1 = *reinterpret_cast<const float4*>(wp + p + 4);
            float g0 = h[(size_t)c0.x * H1_ + f];
            float g1 = h[(size_t)c0.y * H1_ + f];
            float g2 = h[(size_t)c0.z * H1_ + f];
            float g3 = h[(size_t)c0.w * H1_ + f];
            float g4 = h[(size_t)c1.x * H1_ + f];
            float g5 = h[(size_t)c1.y * H1_ + f];
            float g6 = h[(size_t)c1.z * H1_ + f];
            float g7 = h[(size_t)c1.w * H1_ + f];
            acc = fmaf(w0.x, g0, acc);
            acc = fmaf(w0.y, g1, acc);
            acc = fmaf(w0.z, g2, acc);
            acc = fmaf(w0.w, g3, acc);
            acc = fmaf(w1.x, g4, acc);
            acc = fmaf(w1.y, g5, acc);
            acc = fmaf(w1.z, g6, acc);
            acc = fmaf(w1.w, g7, acc);
        }
        for (; p < deg; ++p)
            acc = fmaf(wp[p], h[(size_t)cp[p] * H1_ + f], acc);
    }
    sh1[rl][f] = fmaxf(acc, 0.f);     // relu fused here
    __syncthreads();

    if (t < 128) {
        const int r2l = t >> 4;       // 0..7
        const int c   = t & (H2_ - 1);
        const int r2  = blockIdx.x * 8 + r2l;
        if (r2 < N_) {
            float a = 0.f;
#pragma unroll
            for (int k = 0; k < H1_; ++k)
                a = fmaf(sh1[r2l][k], sW2[k * H2_ + c], a);
            h2[(size_t)r2 * H2_ + c] = a;
        }
    }
}

// ---------------- K4: z = A @ h2  (16 rows / block) ----------------
__global__ __launch_bounds__(256) void spmm2(const float* __restrict__ h2,
                                             const int* __restrict__ cursor,
                                             const int* __restrict__ cole,
                                             const float* __restrict__ we,
                                             float* __restrict__ z) {
    const int t = threadIdx.x;
    const int rl = t >> 4;            // 0..15
    const int f  = t & (H2_ - 1);
    const int r  = blockIdx.x * 16 + rl;
    if (r >= N_) return;
    const int deg = cursor[r];
    const int*   cp = cole + (size_t)r * CAP_;
    const float* wp = we   + (size_t)r * CAP_;
    float acc = 0.f;
    int p = 0;
    for (; p + 8 <= deg; p += 8) {
        int4   c0 = *reinterpret_cast<const int4*>(cp + p);
        int4   c1 = *reinterpret_cast<const int4*>(cp + p + 4);
        float4 w0 = *reinterpret_cast<const float4*>(wp + p);
        float4 w1 = *reinterpret_cast<const float4*>(wp + p + 4);
        float g0 = h2[(size_t)c0.x * H2_ + f];
        float g1 = h2[(size_t)c0.y * H2_ + f];
        float g2 = h2[(size_t)c0.z * H2_ + f];
        float g3 = h2[(size_t)c0.w * H2_ + f];
        float g4 = h2[(size_t)c1.x * H2_ + f];
        float g5 = h2[(size_t)c1.y * H2_ + f];
        float g6 = h2[(size_t)c1.z * H2_ + f];
        float g7 = h2[(size_t)c1.w * H2_ + f];
        acc = fmaf(w0.x, g0, acc);
        acc = fmaf(w0.y, g1, acc);
        acc = fmaf(w0.z, g2, acc);
        acc = fmaf(w0.w, g3, acc);
        acc = fmaf(w1.x, g4, acc);
        acc = fmaf(w1.y, g5, acc);
        acc = fmaf(w1.z, g6, acc);
        acc = fmaf(w1.w, g7, acc);
    }
    for (; p < deg; ++p)
        acc = fmaf(wp[p], h2[(size_t)cp[p] * H2_ + f], acc);
    z[(size_t)r * H2_ + f] = acc;
}

// ---------------- K5: out = z @ z^T  (R13 body + XCD-chunked swizzle) ------
constexpr int BI = 64;
constexpr int BJ = 256;
constexpr int NBX = (N_ + BJ - 1) / BJ;      // 40  j-blocks (gridDim.x)
constexpr int NBY = (N_ + BI - 1) / BI;      // 157 i-blocks (gridDim.y)
constexpr int NBLK = NBX * NBY;              // 6280; 6280 % 8 == 0 -> bijective
constexpr int CHUNK = NBLK / 8;              // 785 blocks per XCD

__global__ __launch_bounds__(256) void zzt(const float* __restrict__ z,
                                           float* __restrict__ out) {
    __shared__ float zi[H2_][BI + 4];    // 16 x 68
    __shared__ float zj[H2_][BJ + 8];    // 16 x 264
    const int t = threadIdx.x;

    // XCD-chunked swizzle: hw id -> contiguous virtual range per XCD.
    const int lin = blockIdx.y * NBX + blockIdx.x;       // hw dispatch order
    const int v   = (lin & 7) * CHUNK + (lin >> 3);      // bijective (6280%8==0)
    const int by  = v / NBX;                             // i-block
    const int bx  = v % NBX;                             // j-block
    const int ib  = by * BI;
    const int jb  = bx * BJ;

    // stage zi: 64 rows x 16k. thread -> (row = t>>2, kq = (t&3)*4)
    {
        int row = t >> 2;
        int kq  = (t & 3) * 4;
        int gr  = ib + row;
        float4 val = (gr < N_)
            ? *reinterpret_cast<const float4*>(z + (size_t)gr * H2_ + kq)
            : make_float4(0.f, 0.f, 0.f, 0.f);
        zi[kq + 0][row] = val.x;
        zi[kq + 1][row] = val.y;
        zi[kq + 2][row] = val.z;
        zi[kq + 3][row] = val.w;
    }
    // stage zj: 256 rows x 16k, 4 iterations
#pragma unroll
    for (int it = 0; it < 4; ++it) {
        int idx = it * 256 + t;
        int row = idx >> 2;
        int kq  = (idx & 3) * 4;
        int gr  = jb + row;
        float4 val = (gr < N_)
            ? *reinterpret_cast<const float4*>(z + (size_t)gr * H2_ + kq)
            : make_float4(0.f, 0.f, 0.f, 0.f);
        zj[kq + 0][row] = val.x;
        zj[kq + 1][row] = val.y;
        zj[kq + 2][row] = val.z;
        zj[kq + 3][row] = val.w;
    }
    __syncthreads();

    const int tj = t & 31;          // 32 j-lanes
    const int i0 = (t >> 5) * 8;    // 8 i-groups of 8 rows

    float4 accA[8] = {};            // j = jb + tj*4 .. +3
    float4 accB[8] = {};            // j = jb + 128 + tj*4 .. +3

#pragma unroll
    for (int k = 0; k < H2_; ++k) {
        float4 b0 = *reinterpret_cast<const float4*>(&zj[k][tj * 4]);
        float4 b1 = *reinterpret_cast<const float4*>(&zj[k][128 + tj * 4]);
        float4 a0 = *reinterpret_cast<const float4*>(&zi[k][i0]);      // bcast
        float4 a1 = *reinterpret_cast<const float4*>(&zi[k][i0 + 4]);  // bcast
        float av[8] = {a0.x, a0.y, a0.z, a0.w, a1.x, a1.y, a1.z, a1.w};
#pragma unroll
        for (int ii = 0; ii < 8; ++ii) {
            accA[ii].x = fmaf(av[ii], b0.x, accA[ii].x);
            accA[ii].y = fmaf(av[ii], b0.y, accA[ii].y);
            accA[ii].z = fmaf(av[ii], b0.z, accA[ii].z);
            accA[ii].w = fmaf(av[ii], b0.w, accA[ii].w);
            accB[ii].x = fmaf(av[ii], b1.x, accB[ii].x);
            accB[ii].y = fmaf(av[ii], b1.y, accB[ii].y);
            accB[ii].z = fmaf(av[ii], b1.z, accB[ii].z);
            accB[ii].w = fmaf(av[ii], b1.w, accB[ii].w);
        }
    }

    const int j0 = jb + tj * 4;
    const int j1 = jb + 128 + tj * 4;
#pragma unroll
    for (int ii = 0; ii < 8; ++ii) {
        int gi = ib + i0 + ii;
        if (gi >= N_) break;
        float* orow = out + (size_t)gi * N_;
        if (j0 + 3 < N_) {
            f32x4 val = {accA[ii].x, accA[ii].y, accA[ii].z, accA[ii].w};
            __builtin_nontemporal_store(val, reinterpret_cast<f32x4*>(orow + j0));
        } else {
            float a[4] = {accA[ii].x, accA[ii].y, accA[ii].z, accA[ii].w};
            for (int jj = 0; jj < 4; ++jj)
                if (j0 + jj < N_) orow[j0 + jj] = a[jj];
        }
        if (j1 + 3 < N_) {
            f32x4 val = {accB[ii].x, accB[ii].y, accB[ii].z, accB[ii].w};
            __builtin_nontemporal_store(val, reinterpret_cast<f32x4*>(orow + j1));
        } else {
            float b[4] = {accB[ii].x, accB[ii].y, accB[ii].z, accB[ii].w};
            for (int jj = 0; jj < 4; ++jj)
                if (j1 + jj < N_) orow[j1 + jj] = b[jj];
        }
    }
}

extern "C" void kernel_launch(void* const* d_in, const int* in_sizes, int n_in,
                              void* d_out, int out_size, void* d_ws, size_t ws_size,
                              hipStream_t stream) {
    const float* x    = (const float*)d_in[0];
    const float* ew   = (const float*)d_in[1];
    const float* W1   = (const float*)d_in[2];
    const float* W2   = (const float*)d_in[3];
    const int*   erow = (const int*)d_in[4];
    const int*   ecol = (const int*)d_in[5];
    float* out = (float*)d_out;

    // workspace layout (4B elements) — same as R13
    float* h      = (float*)d_ws;              // N*H1
    float* h2     = h  + (size_t)N_ * H1_;     // N*H2
    float* z      = h2 + (size_t)N_ * H2_;     // N*H2
    float* we     = z  + (size_t)N_ * H2_;     // N*CAP
    int*   cole   = (int*)(we + (size_t)N_ * CAP_);   // N*CAP
    int*   cursor = cole + (size_t)N_ * CAP_;  // N

    gemm_xw1_zero<<<GEMM_BLOCKS + ZERO_BLOCKS, 256, 0, stream>>>(x, W1, h, cursor);
    scatter_ell<<<(E_ + 255) / 256, 256, 0, stream>>>(erow, ecol, ew, cursor, cole, we);
    spmm1_mlp<<<(N_ + 7) / 8, 256, 0, stream>>>(h, cursor, cole, we, W2, h2);
    spmm2<<<(N_ + 15) / 16, 256, 0, stream>>>(h2, cursor, cole, we, z);

    dim3 grid(NBX, NBY);   // 40 x 157
    zzt<<<grid, 256, 0, stream>>>(z, out);
}